// Round 2
// 277.278 us; speedup vs baseline: 1.0021x; 1.0021x over previous
//
#include <hip/hip_runtime.h>
#include <hip/hip_bf16.h>

#define N_NODES 131072
#define DIM 128
#define NG 512

typedef __bf16 bf16;
typedef __attribute__((ext_vector_type(8))) __bf16 bf16x8;
typedef __attribute__((ext_vector_type(4))) float f32x4;

// 1/sqrt(128) * log2(e) — folded into Wk/bk so attention scores exp2 directly
#define KSC 0.12753785006196978f

// workspace layout (bytes)
#define WS_STARTS 0                         // 513 ints
#define WS_WF     8192                      // fragment-ordered W: 3*8*4*64*8 bf16 = 98304 B
#define WS_KB     131072                    // N*128 bf16
#define WS_QB     (131072 + 33554432)
#define WS_VTB    (131072 + 2*33554432)     // Vt[d][n]: 128 x N bf16

__device__ __forceinline__ void gl_lds16(const void* g, void* l) {
    __builtin_amdgcn_global_load_lds(
        (const __attribute__((address_space(1))) unsigned int*)g,
        (__attribute__((address_space(3))) unsigned int*)l, 16, 0, 0);
}

__global__ void seg_starts_kernel(const int* __restrict__ batch, int* __restrict__ starts) {
    int g = threadIdx.x;                    // 0..511
    int lo = 0, hi = N_NODES;
    while (lo < hi) { int mid = (lo + hi) >> 1; if (batch[mid] < g) lo = mid + 1; else hi = mid; }
    starts[g] = lo;
    if (g == 0) starts[NG] = N_NODES;
}

// Emit W in B-fragment order: Wf[((mat*8+n0)*4+ks)*64 + lane] is the bf16x8 that
// lane reads for MFMA (col = n0*16 + (lane&15), k = ks*32 + (lane>>4)*8 + j).
// Wk (mat 0) is pre-scaled by KSC so attention scores are exp2-ready.
__global__ void wconv_kernel(const float* __restrict__ Wk, const float* __restrict__ Wq,
                             const float* __restrict__ Wv, bf16* __restrict__ Wf) {
    int f = blockIdx.x * 256 + threadIdx.x;  // 0..6143
    int lane = f & 63, ks = (f >> 6) & 3, n0 = (f >> 8) & 7, mat = f >> 11;
    const float* src = (mat == 0) ? Wk : ((mat == 1) ? Wq : Wv);
    float sc = (mat == 0) ? KSC : 1.0f;
    int col = n0 * 16 + (lane & 15);
    int koff = ks * 32 + (lane >> 4) * 8;
    const float* p = src + col * DIM + koff;
    bf16* dst = Wf + (size_t)f * 8;
    #pragma unroll
    for (int j = 0; j < 8; j++) dst[j] = (bf16)(p[j] * sc);
}

// QKV projection: out = x @ W^T + b, stored bf16 (x read ONCE per block, 3 mats).
// V stored transposed: Vt[d][n]. All global stores 16B coalesced via LDS tile.
__global__ __launch_bounds__(256) void qkv_kernel(
        const float* __restrict__ x, const bf16* __restrict__ Wf,
        const float* __restrict__ bk, const float* __restrict__ bq, const float* __restrict__ bv,
        bf16* __restrict__ Kb, bf16* __restrict__ Qb, bf16* __restrict__ Vtb) {
    __shared__ bf16 tile[128 * 136];         // 34816 B; x-tile first, then C-tile per mat
    const int tid = threadIdx.x;
    const int w = tid >> 6, lane = tid & 63, q = lane >> 4, i = lane & 15;
    const int r0 = blockIdx.x * 128;

    {   // stage x tile (coalesced fp32 loads -> bf16 LDS)
        #pragma unroll
        for (int it = 0; it < 16; it++) {
            int e = tid * 4 + it * 1024;     // element in 128x128 tile
            int row = e >> 7, col = e & 127;
            float4 u = *(const float4*)(x + (size_t)(r0 + row) * DIM + col);
            bf16 b[4] = {(bf16)u.x, (bf16)u.y, (bf16)u.z, (bf16)u.w};
            *(ushort4*)&tile[row * 136 + col] = *(ushort4*)b;
        }
    }
    __syncthreads();

    // A fragments from LDS: rows r0 + w*32 + rg*16 + i
    bf16x8 af[2][4];
    #pragma unroll
    for (int rg = 0; rg < 2; rg++)
        #pragma unroll
        for (int ks = 0; ks < 4; ks++)
            af[rg][ks] = *(const bf16x8*)&tile[(w * 32 + rg * 16 + i) * 136 + ks * 32 + q * 8];
    __syncthreads();                         // frag reads done before tile reuse

    for (int mat = 0; mat < 3; mat++) {
        const float* bias = (mat == 0) ? bk : ((mat == 1) ? bq : bv);
        const float bscale = (mat == 0) ? KSC : 1.0f;
        for (int n0 = 0; n0 < 8; n0++) {
            int col = n0 * 16 + i;
            float bias_v = bias[col] * bscale;
            f32x4 acc0 = {0,0,0,0}, acc1 = {0,0,0,0};
            #pragma unroll
            for (int ks = 0; ks < 4; ks++) {
                bf16x8 bw = *(const bf16x8*)(Wf + ((size_t)((mat * 8 + n0) * 4 + ks) * 64 + lane) * 8);
                acc0 = __builtin_amdgcn_mfma_f32_16x16x32_bf16(af[0][ks], bw, acc0, 0, 0, 0);
                acc1 = __builtin_amdgcn_mfma_f32_16x16x32_bf16(af[1][ks], bw, acc1, 0, 0, 0);
            }
            #pragma unroll
            for (int rg = 0; rg < 2; rg++) {
                f32x4 a = rg ? acc1 : acc0;
                #pragma unroll
                for (int r = 0; r < 4; r++) {
                    int rowl = w * 32 + rg * 16 + q * 4 + r;
                    bf16 hv = (bf16)(a[r] + bias_v);
                    if (mat < 2) tile[rowl * 136 + col] = hv;   // row-major [row][d]
                    else         tile[col * 136 + rowl] = hv;   // transposed [d][row]
                }
            }
        }
        __syncthreads();
        {   // coalesced 16B stores
            int row = tid >> 1, half = tid & 1;
            const uint4* src = (const uint4*)(tile + row * 136 + half * 64);
            uint4* dst;
            if (mat == 0)      dst = (uint4*)(Kb  + (size_t)(r0 + row) * DIM + half * 64);
            else if (mat == 1) dst = (uint4*)(Qb  + (size_t)(r0 + row) * DIM + half * 64);
            else               dst = (uint4*)(Vtb + (size_t)row * N_NODES + r0 + half * 64);
            #pragma unroll
            for (int j = 0; j < 8; j++) dst[j] = src[j];
        }
        __syncthreads();
    }
}

// Fused segment attention + residual + LayerNorm.
// Latency-bound fix (MfmaUtil 8%, VALUBusy 19%, HBM 24%, all idle):
//  - 4 waves x 32 l-rows (was 8 x 16): halves redundant per-wave LDS B-frag reads,
//    doubles per-wave MFMA ILP (64 MFMA/chunk, 16 independent accumulators).
//  - async double-buffered Q/Vt staging via global_load_lds (16B/lane DMA):
//    issue chunk mc+1 right after the single per-chunk barrier, compute mc meanwhile.
//    One __syncthreads per chunk (its vmcnt(0) drain IS the pipeline wait).
//  - pad-free XOR-swizzled LDS (slot ^= row&7). global_load_lds writes linearly, so
//    the swizzle is applied by permuting the per-lane GLOBAL source address (m173
//    pattern); reads apply the same XOR. Conflict-free in 8-lane groups.
//    LDS = 2*16K (Qs) + 2*16K (Vts) + 16K (Ps) = 80 KB -> exactly 2 blocks/CU.
__global__ __launch_bounds__(256, 2) void attn_kernel(
        const float* __restrict__ x,
        const bf16* __restrict__ Kb, const bf16* __restrict__ Qb, const bf16* __restrict__ Vtb,
        const float* __restrict__ gamma, const float* __restrict__ beta,
        const int* __restrict__ starts, float* __restrict__ out) {
    __shared__ bf16 Qs[2][64 * 128];         // 2 x 16384 B, rows m (chunk), swizzled slots
    __shared__ bf16 Vts[2][128 * 64];        // 2 x 16384 B, rows d, swizzled slots
    __shared__ bf16 Ps[4][32 * 64];          // 16384 B, per-wave P scratch, swizzled

    const int g = blockIdx.y;
    const int seg = starts[g];
    const int c = starts[g + 1] - seg;
    const int l0 = blockIdx.x * 128;
    if (l0 >= c) return;

    const int tid = threadIdx.x;
    const int w = tid >> 6, lane = tid & 63, q = lane >> 4, i = lane & 15;

    const int mstart = seg & ~7;             // 8-aligned -> 16B-aligned staging
    const int nch = (seg - mstart + c + 63) >> 6;

    // async-stage one 64-m chunk: Q rows (64x128) + Vt rows (128x64), swizzled source
    auto stage = [&](int buf, int mb) {
        const int rb = w * 16;               // wave's 16 Q rows
        #pragma unroll
        for (int p = 0; p < 4; p++) {
            int row = rb + p * 4 + (lane >> 4);          // LDS row 0..63
            int gr = mb + row; if (gr > N_NODES - 1) gr = N_NODES - 1;
            gl_lds16(Qb + (size_t)gr * DIM + (((lane & 15) ^ (row & 7)) << 3),
                     &Qs[buf][(rb + p * 4) * 128]);
        }
        const int db = w * 32;               // wave's 32 Vt rows
        #pragma unroll
        for (int p = 0; p < 4; p++) {
            int d = db + p * 8 + (lane >> 3);            // LDS row 0..127
            int mo = mb + (((lane & 7) ^ (d & 7)) << 3);
            if (mo > N_NODES - 8) mo = N_NODES - 8;
            gl_lds16(Vtb + (size_t)d * N_NODES + mo,
                     &Vts[buf][(db + p * 8) * 64]);
        }
    };

    stage(0, mstart);                        // chunk 0 in flight during afK loads

    // K A-fragments direct from global (row clamped into segment)
    bf16x8 afK[2][4];
    #pragma unroll
    for (int rg = 0; rg < 2; rg++) {
        int lrow = l0 + w * 32 + rg * 16 + i;
        if (lrow > c - 1) lrow = c - 1;
        const bf16* krow = Kb + (size_t)(seg + lrow) * DIM;
        #pragma unroll
        for (int ks = 0; ks < 4; ks++)
            afK[rg][ks] = *(const bf16x8*)(krow + ks * 32 + q * 8);
    }

    float li[2][4] = {{0,0,0,0},{0,0,0,0}};
    f32x4 Oc[2][8];
    #pragma unroll
    for (int rg = 0; rg < 2; rg++)
        #pragma unroll
        for (int t = 0; t < 8; t++) Oc[rg][t] = (f32x4){0,0,0,0};

    bf16* Pw = Ps[w];
    const int f7 = i & 7;                    // LDS row&7 for all fragment rows (=i&7)
    const int mh = (i >> 3);                 // + 2*ti gives m>>3

    for (int mc = 0; mc < nch; mc++) {
        const int cur = mc & 1;
        const int mbase = mstart + (mc << 6);
        __syncthreads();                     // vmcnt(0): chunk mc landed; readers of buf^1 done
        if (mc + 1 < nch) stage(cur ^ 1, mbase + 64);

        const bf16* QsB = Qs[cur];
        const bf16* VtB = Vts[cur];

        // S = K * Q^T (per wave: 2 x 16 l-rows x 64 m-cols), pre-scaled for exp2
        #pragma unroll
        for (int ti = 0; ti < 4; ti++) {
            f32x4 a0 = {0,0,0,0}, a1 = {0,0,0,0};
            #pragma unroll
            for (int ks = 0; ks < 4; ks++) {
                bf16x8 bq = *(const bf16x8*)&QsB[(ti * 16 + i) * 128 + (((ks * 4 + q) ^ f7) << 3)];
                a0 = __builtin_amdgcn_mfma_f32_16x16x32_bf16(afK[0][ks], bq, a0, 0, 0, 0);
                a1 = __builtin_amdgcn_mfma_f32_16x16x32_bf16(afK[1][ks], bq, a1, 0, 0, 0);
            }
            if (mc == 0 || mc == nch - 1) {  // only edge chunks can have invalid m
                int mg = mbase + ti * 16 + i;
                if (mg < seg || mg >= seg + c) {
                    a0 = (f32x4){-1.0e30f, -1.0e30f, -1.0e30f, -1.0e30f};
                    a1 = a0;
                }
            }
            // p = exp2(s); accumulate l per-lane; write P (C-layout -> A-layout, swizzled)
            int mhi = 2 * ti + mh;           // m>>3
            #pragma unroll
            for (int r = 0; r < 4; r++) {
                int lr = q * 4 + r;          // 0..15 (lr&7 == l&7 for both rg)
                int sl = ((mhi ^ (lr & 7)) << 3) + f7;
                float p0 = exp2f(a0[r]); li[0][r] += p0;
                Pw[lr * 64 + sl] = (bf16)p0;
                float p1 = exp2f(a1[r]); li[1][r] += p1;
                Pw[(16 + lr) * 64 + sl] = (bf16)p1;
            }
        }

        bf16x8 afP[2][2];
        #pragma unroll
        for (int rg = 0; rg < 2; rg++)
            #pragma unroll
            for (int k2 = 0; k2 < 2; k2++)
                afP[rg][k2] = *(const bf16x8*)&Pw[(rg * 16 + i) * 64 + (((k2 * 4 + q) ^ f7) << 3)];

        #pragma unroll
        for (int dt = 0; dt < 8; dt++) {
            #pragma unroll
            for (int k2 = 0; k2 < 2; k2++) {
                bf16x8 bv = *(const bf16x8*)&VtB[(dt * 16 + i) * 64 + (((k2 * 4 + q) ^ f7) << 3)];
                Oc[0][dt] = __builtin_amdgcn_mfma_f32_16x16x32_bf16(afP[0][k2], bv, Oc[0][dt], 0, 0, 0);
                Oc[1][dt] = __builtin_amdgcn_mfma_f32_16x16x32_bf16(afP[1][k2], bv, Oc[1][dt], 0, 0, 0);
            }
        }
    }

    // one-time l reduction across the 16 i-lanes
    #pragma unroll
    for (int st = 1; st < 16; st <<= 1)
        #pragma unroll
        for (int rg = 0; rg < 2; rg++)
            #pragma unroll
            for (int r = 0; r < 4; r++)
                li[rg][r] += __shfl_xor(li[rg][r], st);

    // epilogue: z = O/l, h = x + z, LayerNorm, store fp32
    float gv[8], bvv[8];
    #pragma unroll
    for (int t = 0; t < 8; t++) { gv[t] = gamma[t * 16 + i]; bvv[t] = beta[t * 16 + i]; }
    #pragma unroll
    for (int rg = 0; rg < 2; rg++)
        for (int r = 0; r < 4; r++) {
            int lg = l0 + w * 32 + rg * 16 + q * 4 + r;
            if (lg >= c) continue;           // uniform across the 16-lane shuffle group
            size_t node = (size_t)(seg + lg);
            float inv = 1.0f / li[rg][r];
            const float* xr = x + node * DIM;
            float h[8], sum = 0.0f, ss = 0.0f;
            #pragma unroll
            for (int t = 0; t < 8; t++) {
                float hv = xr[t * 16 + i] + Oc[rg][t][r] * inv;
                h[t] = hv;
                sum += hv; ss += hv * hv;
            }
            #pragma unroll
            for (int st = 1; st < 16; st <<= 1) {
                sum += __shfl_xor(sum, st);
                ss  += __shfl_xor(ss, st);
            }
            float mu = sum * (1.0f / 128.0f);
            float var = ss * (1.0f / 128.0f) - mu * mu;
            float rstd = rsqrtf(var + 1e-5f);
            float* op = out + node * DIM;
            #pragma unroll
            for (int t = 0; t < 8; t++)
                op[t * 16 + i] = (h[t] - mu) * rstd * gv[t] + bvv[t];
        }
}

extern "C" void kernel_launch(void* const* d_in, const int* in_sizes, int n_in,
                              void* d_out, int out_size, void* d_ws, size_t ws_size,
                              hipStream_t stream) {
    (void)in_sizes; (void)n_in; (void)out_size; (void)ws_size;
    const float* x     = (const float*)d_in[0];
    const float* Wk    = (const float*)d_in[1];
    const float* bk    = (const float*)d_in[2];
    const float* Wq    = (const float*)d_in[3];
    const float* bq    = (const float*)d_in[4];
    const float* Wv    = (const float*)d_in[5];
    const float* bv    = (const float*)d_in[6];
    const float* gamma = (const float*)d_in[7];
    const float* beta  = (const float*)d_in[8];
    const int*   batch = (const int*)d_in[9];
    float* out = (float*)d_out;

    char* ws = (char*)d_ws;
    int*  starts = (int*)(ws + WS_STARTS);
    bf16* Wf  = (bf16*)(ws + WS_WF);
    bf16* Kb  = (bf16*)(ws + WS_KB);
    bf16* Qb  = (bf16*)(ws + WS_QB);
    bf16* Vtb = (bf16*)(ws + WS_VTB);

    seg_starts_kernel<<<1, 512, 0, stream>>>(batch, starts);
    wconv_kernel<<<24, 256, 0, stream>>>(Wk, Wq, Wv, Wf);
    qkv_kernel<<<1024, 256, 0, stream>>>(x, Wf, bk, bq, bv, Kb, Qb, Vtb);
    attn_kernel<<<dim3(4, NG), 256, 0, stream>>>(x, Kb, Qb, Vtb, gamma, beta, starts, out);
}

// Round 3
// 274.544 us; speedup vs baseline: 1.0121x; 1.0100x over previous
//
#include <hip/hip_runtime.h>
#include <hip/hip_bf16.h>

#define N_NODES 131072
#define DIM 128
#define NG 512

typedef __bf16 bf16;
typedef __attribute__((ext_vector_type(8))) __bf16 bf16x8;
typedef __attribute__((ext_vector_type(4))) float f32x4;

// 1/sqrt(128) * log2(e) — folded into Wk/bk so attention scores exp2 directly
#define KSC 0.12753785006196978f

// workspace layout (bytes)
#define WS_STARTS 0                         // 513 ints
#define WS_WF     8192                      // fragment-ordered W: 3*8*4*64*8 bf16 = 98304 B
#define WS_KB     131072                    // N*128 bf16
#define WS_QB     (131072 + 33554432)
#define WS_VTB    (131072 + 2*33554432)     // Vt[d][n]: 128 x N bf16

__device__ __forceinline__ void gl_lds16(const void* g, void* l) {
    __builtin_amdgcn_global_load_lds(
        (const __attribute__((address_space(1))) unsigned int*)g,
        (__attribute__((address_space(3))) unsigned int*)l, 16, 0, 0);
}

__global__ void seg_starts_kernel(const int* __restrict__ batch, int* __restrict__ starts) {
    int g = threadIdx.x;                    // 0..511
    int lo = 0, hi = N_NODES;
    while (lo < hi) { int mid = (lo + hi) >> 1; if (batch[mid] < g) lo = mid + 1; else hi = mid; }
    starts[g] = lo;
    if (g == 0) starts[NG] = N_NODES;
}

// Emit W in B-fragment order: Wf[((mat*8+n0)*4+ks)*64 + lane] is the bf16x8 that
// lane reads for MFMA (col = n0*16 + (lane&15), k = ks*32 + (lane>>4)*8 + j).
// Wk (mat 0) is pre-scaled by KSC so attention scores are exp2-ready.
__global__ void wconv_kernel(const float* __restrict__ Wk, const float* __restrict__ Wq,
                             const float* __restrict__ Wv, bf16* __restrict__ Wf) {
    int f = blockIdx.x * 256 + threadIdx.x;  // 0..6143
    int lane = f & 63, ks = (f >> 6) & 3, n0 = (f >> 8) & 7, mat = f >> 11;
    const float* src = (mat == 0) ? Wk : ((mat == 1) ? Wq : Wv);
    float sc = (mat == 0) ? KSC : 1.0f;
    int col = n0 * 16 + (lane & 15);
    int koff = ks * 32 + (lane >> 4) * 8;
    const float* p = src + col * DIM + koff;
    bf16* dst = Wf + (size_t)f * 8;
    #pragma unroll
    for (int j = 0; j < 8; j++) dst[j] = (bf16)(p[j] * sc);
}

// QKV projection: out = x @ W^T + b, stored bf16 (x read ONCE per block, 3 mats).
// V stored transposed: Vt[d][n]. All global stores 16B coalesced via LDS tile.
__global__ __launch_bounds__(256) void qkv_kernel(
        const float* __restrict__ x, const bf16* __restrict__ Wf,
        const float* __restrict__ bk, const float* __restrict__ bq, const float* __restrict__ bv,
        bf16* __restrict__ Kb, bf16* __restrict__ Qb, bf16* __restrict__ Vtb) {
    __shared__ bf16 tile[128 * 136];         // 34816 B; x-tile first, then C-tile per mat
    const int tid = threadIdx.x;
    const int w = tid >> 6, lane = tid & 63, q = lane >> 4, i = lane & 15;
    const int r0 = blockIdx.x * 128;

    {   // stage x tile (coalesced fp32 loads -> bf16 LDS)
        #pragma unroll
        for (int it = 0; it < 16; it++) {
            int e = tid * 4 + it * 1024;     // element in 128x128 tile
            int row = e >> 7, col = e & 127;
            float4 u = *(const float4*)(x + (size_t)(r0 + row) * DIM + col);
            bf16 b[4] = {(bf16)u.x, (bf16)u.y, (bf16)u.z, (bf16)u.w};
            *(ushort4*)&tile[row * 136 + col] = *(ushort4*)b;
        }
    }
    __syncthreads();

    // A fragments from LDS: rows r0 + w*32 + rg*16 + i
    bf16x8 af[2][4];
    #pragma unroll
    for (int rg = 0; rg < 2; rg++)
        #pragma unroll
        for (int ks = 0; ks < 4; ks++)
            af[rg][ks] = *(const bf16x8*)&tile[(w * 32 + rg * 16 + i) * 136 + ks * 32 + q * 8];
    __syncthreads();                         // frag reads done before tile reuse

    for (int mat = 0; mat < 3; mat++) {
        const float* bias = (mat == 0) ? bk : ((mat == 1) ? bq : bv);
        const float bscale = (mat == 0) ? KSC : 1.0f;
        for (int n0 = 0; n0 < 8; n0++) {
            int col = n0 * 16 + i;
            float bias_v = bias[col] * bscale;
            f32x4 acc0 = {0,0,0,0}, acc1 = {0,0,0,0};
            #pragma unroll
            for (int ks = 0; ks < 4; ks++) {
                bf16x8 bw = *(const bf16x8*)(Wf + ((size_t)((mat * 8 + n0) * 4 + ks) * 64 + lane) * 8);
                acc0 = __builtin_amdgcn_mfma_f32_16x16x32_bf16(af[0][ks], bw, acc0, 0, 0, 0);
                acc1 = __builtin_amdgcn_mfma_f32_16x16x32_bf16(af[1][ks], bw, acc1, 0, 0, 0);
            }
            #pragma unroll
            for (int rg = 0; rg < 2; rg++) {
                f32x4 a = rg ? acc1 : acc0;
                #pragma unroll
                for (int r = 0; r < 4; r++) {
                    int rowl = w * 32 + rg * 16 + q * 4 + r;
                    bf16 hv = (bf16)(a[r] + bias_v);
                    if (mat < 2) tile[rowl * 136 + col] = hv;   // row-major [row][d]
                    else         tile[col * 136 + rowl] = hv;   // transposed [d][row]
                }
            }
        }
        __syncthreads();
        {   // coalesced 16B stores
            int row = tid >> 1, half = tid & 1;
            const uint4* src = (const uint4*)(tile + row * 136 + half * 64);
            uint4* dst;
            if (mat == 0)      dst = (uint4*)(Kb  + (size_t)(r0 + row) * DIM + half * 64);
            else if (mat == 1) dst = (uint4*)(Qb  + (size_t)(r0 + row) * DIM + half * 64);
            else               dst = (uint4*)(Vtb + (size_t)row * N_NODES + r0 + half * 64);
            #pragma unroll
            for (int j = 0; j < 8; j++) dst[j] = src[j];
        }
        __syncthreads();
    }
}

// Fused segment attention + residual + LayerNorm.
// R2: occupancy fix. Evidence: both prior rounds ran ~1 block/CU (avg 3.3 waves/CU;
// block lifetime ~19us; 5 serial blocks/CU ~= duration). R1's 81920B LDS x2 ==
// exactly 160KiB -> any reserved byte kills the 2nd block.
//  - 8 waves x 16 l-rows (512 thr), LDS cut to 64KB -> 2 blocks/CU = 16 waves/CU.
//  - P overlay: P lives in Qs[cur]'s dead window (dead after QK^T reads; only
//    DMA-rewritten after the NEXT top __syncthreads). Needs one mid-chunk barrier
//    implemented as raw s_barrier + lgkmcnt(0) ONLY (no vmcnt drain) so the
//    just-issued next-chunk DMA stays in flight.
//  - keeps R1's verified swizzled both-sides staging + double-buffered DMA.
__global__ __launch_bounds__(512, 4) void attn_kernel(
        const float* __restrict__ x,
        const bf16* __restrict__ Kb, const bf16* __restrict__ Qb, const bf16* __restrict__ Vtb,
        const float* __restrict__ gamma, const float* __restrict__ beta,
        const int* __restrict__ starts, float* __restrict__ out) {
    __shared__ bf16 Qs[2][64 * 128];         // 2 x 16384 B; P overlays Qs[cur] post-QK^T
    __shared__ bf16 Vts[2][128 * 64];        // 2 x 16384 B   (total 65536 B -> 2 blocks/CU)

    const int g = blockIdx.y;
    const int seg = starts[g];
    const int c = starts[g + 1] - seg;
    const int l0 = blockIdx.x * 128;
    if (l0 >= c) return;

    const int tid = threadIdx.x;
    const int w = tid >> 6, lane = tid & 63, q = lane >> 4, i = lane & 15;

    const int mstart = seg & ~7;             // 8-aligned -> 16B-aligned staging
    const int nch = (seg - mstart + c + 63) >> 6;

    // async-stage one 64-m chunk: Q rows (64x128) + Vt rows (128x64), swizzled source.
    // 4 gl_lds16 per wave (2 Q + 2 Vt); LDS dest wave-uniform base + lane*16B.
    auto stage = [&](int buf, int mb) {
        #pragma unroll
        for (int p = 0; p < 2; p++) {        // Q: 1 instr = 4 rows (16 lanes/row)
            int row = w * 8 + p * 4 + (lane >> 4);
            int gr = mb + row; if (gr > N_NODES - 1) gr = N_NODES - 1;
            gl_lds16(Qb + (size_t)gr * DIM + (((lane & 15) ^ (row & 7)) << 3),
                     &Qs[buf][(w * 8 + p * 4) * 128]);
        }
        #pragma unroll
        for (int p = 0; p < 2; p++) {        // Vt: 1 instr = 8 rows (8 lanes/row)
            int d = w * 16 + p * 8 + (lane >> 3);
            int mo = mb + (((lane & 7) ^ (d & 7)) << 3);
            if (mo > N_NODES - 8) mo = N_NODES - 8;
            gl_lds16(Vtb + (size_t)d * N_NODES + mo,
                     &Vts[buf][(w * 16 + p * 8) * 64]);
        }
    };

    stage(0, mstart);                        // chunk 0 in flight during afK loads

    // K fragments direct from global (row clamped into segment); 16 l-rows per wave
    bf16x8 afK[4];
    {
        int lrow = l0 + w * 16 + i;
        if (lrow > c - 1) lrow = c - 1;
        const bf16* krow = Kb + (size_t)(seg + lrow) * DIM;
        #pragma unroll
        for (int ks = 0; ks < 4; ks++)
            afK[ks] = *(const bf16x8*)(krow + ks * 32 + q * 8);
    }

    float li[4] = {0.0f, 0.0f, 0.0f, 0.0f};
    f32x4 Oc[8];
    #pragma unroll
    for (int t = 0; t < 8; t++) Oc[t] = (f32x4){0,0,0,0};

    const int f7 = i & 7;                    // LDS row&7 for all fragment rows (=i&7)
    const int mh = (i >> 3);

    for (int mc = 0; mc < nch; mc++) {
        const int cur = mc & 1;
        const int mbase = mstart + (mc << 6);
        __syncthreads();                     // vmcnt(0): chunk mc landed; all prev LDS refs done
        if (mc + 1 < nch) stage(cur ^ 1, mbase + 64);

        const bf16* QsB = Qs[cur];
        const bf16* VtB = Vts[cur];
        bf16* Pw = &Qs[cur][w * 1024];       // wave-private 16x64 P slice (overlay)

        // S = K * Q^T (16 l-rows x 64 m-cols per wave), pre-scaled for exp2
        f32x4 s[4];
        __builtin_amdgcn_s_setprio(1);
        #pragma unroll
        for (int ti = 0; ti < 4; ti++) {
            f32x4 acc = {0,0,0,0};
            #pragma unroll
            for (int ks = 0; ks < 4; ks++) {
                bf16x8 bq = *(const bf16x8*)&QsB[(ti * 16 + i) * 128 + (((ks * 4 + q) ^ f7) << 3)];
                acc = __builtin_amdgcn_mfma_f32_16x16x32_bf16(afK[ks], bq, acc, 0, 0, 0);
            }
            s[ti] = acc;
        }
        __builtin_amdgcn_s_setprio(0);
        if (mc == 0 || mc == nch - 1) {      // only edge chunks can have invalid m
            #pragma unroll
            for (int ti = 0; ti < 4; ti++) {
                int mg = mbase + ti * 16 + i;
                bool valid = (mg >= seg) && (mg < seg + c);
                if (!valid) s[ti] = (f32x4){-1.0e30f, -1.0e30f, -1.0e30f, -1.0e30f};
            }
        }
        // p = exp2(s) in registers (overlaps barrier wait); accumulate l per-lane
        #pragma unroll
        for (int ti = 0; ti < 4; ti++)
            #pragma unroll
            for (int r = 0; r < 4; r++) {
                float pv = exp2f(s[ti][r]);
                li[r] += pv;
                s[ti][r] = pv;
            }

        // raw barrier: all waves' Qs[cur] reads retired; DMA (vmcnt) stays in flight
        asm volatile("s_waitcnt lgkmcnt(0)" ::: "memory");
        __builtin_amdgcn_s_barrier();
        asm volatile("" ::: "memory");

        // write P into overlay (C-layout -> A-layout, swizzled)
        #pragma unroll
        for (int ti = 0; ti < 4; ti++) {
            int mhi = 2 * ti + mh;           // m>>3
            #pragma unroll
            for (int r = 0; r < 4; r++) {
                int lr = q * 4 + r;
                Pw[lr * 64 + ((mhi ^ (lr & 7)) << 3) + f7] = (bf16)s[ti][r];
            }
        }

        // read P as A-fragments (same-wave LDS FIFO: no barrier needed)
        bf16x8 afP[2];
        #pragma unroll
        for (int k2 = 0; k2 < 2; k2++)
            afP[k2] = *(const bf16x8*)&Pw[i * 64 + (((k2 * 4 + q) ^ f7) << 3)];

        __builtin_amdgcn_s_setprio(1);
        #pragma unroll
        for (int dt = 0; dt < 8; dt++) {
            #pragma unroll
            for (int k2 = 0; k2 < 2; k2++) {
                bf16x8 bv = *(const bf16x8*)&VtB[(dt * 16 + i) * 64 + (((k2 * 4 + q) ^ f7) << 3)];
                Oc[dt] = __builtin_amdgcn_mfma_f32_16x16x32_bf16(afP[k2], bv, Oc[dt], 0, 0, 0);
            }
        }
        __builtin_amdgcn_s_setprio(0);
    }

    // one-time l reduction across the 16 i-lanes
    #pragma unroll
    for (int st = 1; st < 16; st <<= 1)
        #pragma unroll
        for (int r = 0; r < 4; r++)
            li[r] += __shfl_xor(li[r], st);

    // epilogue: z = O/l, h = x + z, LayerNorm, store fp32
    float gv[8], bvv[8];
    #pragma unroll
    for (int t = 0; t < 8; t++) { gv[t] = gamma[t * 16 + i]; bvv[t] = beta[t * 16 + i]; }
    for (int r = 0; r < 4; r++) {
        int lg = l0 + w * 16 + q * 4 + r;
        if (lg >= c) continue;               // uniform across the 16-lane shuffle group
        size_t node = (size_t)(seg + lg);
        float inv = 1.0f / li[r];
        const float* xr = x + node * DIM;
        float h[8], sum = 0.0f, ss = 0.0f;
        #pragma unroll
        for (int t = 0; t < 8; t++) {
            float hv = xr[t * 16 + i] + Oc[t][r] * inv;
            h[t] = hv;
            sum += hv; ss += hv * hv;
        }
        #pragma unroll
        for (int st = 1; st < 16; st <<= 1) {
            sum += __shfl_xor(sum, st);
            ss  += __shfl_xor(ss, st);
        }
        float mu = sum * (1.0f / 128.0f);
        float var = ss * (1.0f / 128.0f) - mu * mu;
        float rstd = rsqrtf(var + 1e-5f);
        float* op = out + node * DIM;
        #pragma unroll
        for (int t = 0; t < 8; t++)
            op[t * 16 + i] = (h[t] - mu) * rstd * gv[t] + bvv[t];
    }
}

extern "C" void kernel_launch(void* const* d_in, const int* in_sizes, int n_in,
                              void* d_out, int out_size, void* d_ws, size_t ws_size,
                              hipStream_t stream) {
    (void)in_sizes; (void)n_in; (void)out_size; (void)ws_size;
    const float* x     = (const float*)d_in[0];
    const float* Wk    = (const float*)d_in[1];
    const float* bk    = (const float*)d_in[2];
    const float* Wq    = (const float*)d_in[3];
    const float* bq    = (const float*)d_in[4];
    const float* Wv    = (const float*)d_in[5];
    const float* bv    = (const float*)d_in[6];
    const float* gamma = (const float*)d_in[7];
    const float* beta  = (const float*)d_in[8];
    const int*   batch = (const int*)d_in[9];
    float* out = (float*)d_out;

    char* ws = (char*)d_ws;
    int*  starts = (int*)(ws + WS_STARTS);
    bf16* Wf  = (bf16*)(ws + WS_WF);
    bf16* Kb  = (bf16*)(ws + WS_KB);
    bf16* Qb  = (bf16*)(ws + WS_QB);
    bf16* Vtb = (bf16*)(ws + WS_VTB);

    seg_starts_kernel<<<1, 512, 0, stream>>>(batch, starts);
    wconv_kernel<<<24, 256, 0, stream>>>(Wk, Wq, Wv, Wf);
    qkv_kernel<<<1024, 256, 0, stream>>>(x, Wf, bk, bq, bv, Kb, Qb, Vtb);
    attn_kernel<<<dim3(4, NG), 512, 0, stream>>>(x, Kb, Qb, Vtb, gamma, beta, starts, out);
}